// Round 13
// baseline (164.485 us; speedup 1.0000x reference)
//
#include <hip/hip_runtime.h>
#include <cstdint>

// RandomMaskSubgraphs — R13: R12 + nontemporal LOADS for all streamed
// operands (edge arrays in mark0/mark1/markdeg/out; mk and planes streams).
// Rationale: 51MB of edge streams can't fit the 4MB/XCD L2 and thrash the
// small gather tables (sb 12.5KB, cand 200KB, dinv 400KB, mk 800KB) that the
// random-access paths depend on. nt loads keep the tables L2-resident.
// (int4/float4 are HIP classes — clang's nontemporal builtins need native
// ext_vector types, hence ix4/fx4 + reinterpret_cast.)
// All numeric logic verbatim from absmax-0.0 rounds (R1/R4/R9/R12).

#define NNODES 100000
#define TWON   200000
#define NBINS  2048
#define SBW    3136     // node-bitmask dwords (3127 used)
#define NLIST  2048
#define NPLANE 256

typedef float fx4 __attribute__((ext_vector_type(4)));
typedef int   ix4 __attribute__((ext_vector_type(4)));

__device__ inline ix4 ntload4(const int4* p) {
    return __builtin_nontemporal_load(reinterpret_cast<const ix4*>(p));
}

__host__ __device__ inline uint32_t rotl32(uint32_t v, int d) {
    return (v << d) | (v >> (32 - d));
}

__host__ __device__ inline void tf2x32(uint32_t k0, uint32_t k1,
                                       uint32_t x0, uint32_t x1,
                                       uint32_t& y0, uint32_t& y1) {
    uint32_t k2 = k0 ^ k1 ^ 0x1BD11BDAu;
    x0 += k0; x1 += k1;
    #pragma unroll
    for (int g = 0; g < 5; ++g) {
        const int ra[4] = {13, 15, 26, 6};
        const int rb[4] = {17, 29, 16, 24};
        if ((g & 1) == 0) {
            #pragma unroll
            for (int j = 0; j < 4; ++j) { x0 += x1; x1 = rotl32(x1, ra[j]); x1 ^= x0; }
        } else {
            #pragma unroll
            for (int j = 0; j < 4; ++j) { x0 += x1; x1 = rotl32(x1, rb[j]); x1 ^= x0; }
        }
        uint32_t ks[3] = {k0, k1, k2};
        x0 += ks[(g + 1) % 3];
        x1 += ks[(g + 2) % 3] + (uint32_t)(g + 1);
    }
    y0 = x0; y1 = x1;
}

__device__ inline float uscore(uint32_t ka, uint32_t kb, uint32_t s) {
    uint32_t y0, y1;
    tf2x32(ka, kb, 0u, s, y0, y1);
    uint32_t fb = 0x3f800000u | ((y0 ^ y1) >> 9);
    return __uint_as_float(fb) - 1.0f;
}

__device__ inline uint32_t sbtest(const uint32_t* sb, int a, int b) {
    return ((sb[a >> 5] >> (a & 31)) | (sb[b >> 5] >> (b & 31))) & 1u;
}

__device__ inline int aload(const int* p) {
    return __hip_atomic_load(p, __ATOMIC_RELAXED, __HIP_MEMORY_SCOPE_AGENT);
}

__device__ inline int binof(float u) {
    int b = (int)(u * 2048.0f);
    return (b > NBINS - 1) ? NBINS - 1 : b;
}

// scal: [0]=cnt0 [1]=cnt1 [2]=tick_h0 [3]=tick_h1 [4]=tick_s0 [5]=tick_s1
//       [8]=T0 [9]=R0 [10]=T1 [11]=R1   (zeroed by k_init each launch)

// init: block 0 builds seed bitmask in LDS and dumps to global sb0;
// blocks 1..gZ zero the [cand | hist0 | hist1 | scal] region.
__global__ __launch_bounds__(256) void k_init(
        const int* __restrict__ seeds, int nSeeds,
        uint32_t* __restrict__ sb0, uint32_t* __restrict__ z, int nz) {
    __shared__ uint32_t seedb[SBW];
    const int t = threadIdx.x;
    if (blockIdx.x == 0) {
        for (int j = t; j < SBW; j += 256) seedb[j] = 0;
        __syncthreads();
        for (int j = t; j < nSeeds; j += 256) {
            int s = seeds[j];
            if (s < NNODES) atomicOr(&seedb[s >> 5], 1u << (s & 31));
        }
        __syncthreads();
        for (int j = t; j < SBW; j += 256) sb0[j] = seedb[j];
    } else {
        int i = (blockIdx.x - 1) * 256 + t;
        if (i < nz) z[i] = 0;
    }
}

// mark iteration 0: global seed bitmask (12.5KB, L1/L2-resident), mk written
// unconditionally; cand byte stores (benign races, plain stores).
__global__ __launch_bounds__(256) void k_mark0(
        const int4* __restrict__ r4, const int4* __restrict__ c4,
        const uint32_t* __restrict__ sb,
        unsigned char* __restrict__ mk, unsigned char* __restrict__ cand,
        int E4) {
    const int i = blockIdx.x * 256 + threadIdx.x;
    if (i >= E4) return;
    ix4 r = ntload4(&r4[i]), c = ntload4(&c4[i]);
    uint32_t m = 0;
    if (sbtest(sb, r.x, c.x)) { m |= 1u; cand[r.x + c.x] = 1; }
    if (sbtest(sb, r.y, c.y)) { m |= 2u; cand[r.y + c.y] = 1; }
    if (sbtest(sb, r.z, c.z)) { m |= 4u; cand[r.z + c.z] = 1; }
    if (sbtest(sb, r.w, c.w)) { m |= 8u; cand[r.w + c.w] = 1; }
    __builtin_nontemporal_store(m ? (unsigned char)m : (unsigned char)0, &mk[i]);
}

// mark iteration 1: mk RMW.
__global__ __launch_bounds__(256) void k_mark1(
        const int4* __restrict__ r4, const int4* __restrict__ c4,
        const uint32_t* __restrict__ sb,
        unsigned char* __restrict__ mk, unsigned char* __restrict__ cand,
        int E4) {
    const int i = blockIdx.x * 256 + threadIdx.x;
    if (i >= E4) return;
    ix4 r = ntload4(&r4[i]), c = ntload4(&c4[i]);
    uint32_t m = mk[i], nm = m;
    if (!(nm & 1u) && sbtest(sb, r.x, c.x)) { nm |= 1u; cand[r.x + c.x] = 1; }
    if (!(nm & 2u) && sbtest(sb, r.y, c.y)) { nm |= 2u; cand[r.y + c.y] = 1; }
    if (!(nm & 4u) && sbtest(sb, r.z, c.z)) { nm |= 4u; cand[r.z + c.z] = 1; }
    if (!(nm & 8u) && sbtest(sb, r.w, c.w)) { nm |= 8u; cand[r.w + c.w] = 1; }
    if (nm != m) mk[i] = (unsigned char)nm;
}

// histogram of candidate score bins; last block scans -> T,R in scal.
__global__ __launch_bounds__(1024) void k_histscan(
        const unsigned char* __restrict__ cand,
        int* __restrict__ hist, int* __restrict__ scal, int iter,
        uint32_t ka, uint32_t kb) {
    __shared__ int lh[NBINS];
    __shared__ int part[1024];
    __shared__ int lastFlag;
    int t = threadIdx.x;
    int s = blockIdx.x * 1024 + t;
    lh[t] = 0; lh[t + 1024] = 0;
    __syncthreads();
    if (s < TWON && cand[s]) {
        atomicAdd(&lh[binof(uscore(ka, kb, (uint32_t)s))], 1);
    }
    __syncthreads();
    if (lh[t]) atomicAdd(&hist[t], lh[t]);
    if (lh[t + 1024]) atomicAdd(&hist[t + 1024], lh[t + 1024]);
    if (t == 0) {
        __threadfence();
        int old = __hip_atomic_fetch_add(&scal[2 + iter], 1, __ATOMIC_ACQ_REL, __HIP_MEMORY_SCOPE_AGENT);
        lastFlag = (old == (int)gridDim.x - 1);
    }
    __syncthreads();
    if (!lastFlag) return;
    // last-block tail: scan 2048 bins -> threshold bin T, in-bin rank R
    int h0 = aload(&hist[2 * t]);
    int h1 = aload(&hist[2 * t + 1]);
    part[t] = h0 + h1;
    __syncthreads();
    for (int d = 1; d < 1024; d <<= 1) {
        int w = (t >= d) ? part[t - d] : 0;
        __syncthreads();
        part[t] += w;
        __syncthreads();
    }
    int total = part[1023];
    int k = total >> (iter + 1);        // floor(count * 0.5^(i+1)), exact
    int base = (t > 0) ? part[t - 1] : 0;
    if (total > 0) {
        if (h0 > 0 && base <= k && k < base + h0) { scal[8 + 2 * iter] = 2 * t;     scal[9 + 2 * iter] = k - base; }
        int b2 = base + h0;
        if (h1 > 0 && b2 <= k && k < b2 + h1)     { scal[8 + 2 * iter] = 2 * t + 1; scal[9 + 2 * iter] = k - b2; }
    }
}

// select: bits (bin<T) via ballot; boundary bin -> glist; zero cand slice;
// last-block exact stable rank tail.
__global__ __launch_bounds__(256) void k_selrank(
        uint32_t* __restrict__ cand32, const unsigned char* __restrict__ cand,
        uint32_t* __restrict__ sbOut, int* __restrict__ scal,
        int* __restrict__ glist, int iter, uint32_t ka, uint32_t kb) {
    __shared__ int lastFlag;
    __shared__ int llist[NLIST];
    __shared__ float lscore[NLIST];
    const int t = threadIdx.x;
    const int b = blockIdx.x;
    const int s = b * 256 + t;
    const int T = scal[8 + 2 * iter];
    const int R = scal[9 + 2 * iter];
    bool cbit = (s < TWON) && cand[s];
    int bin = cbit ? binof(uscore(ka, kb, (uint32_t)s)) : -1;
    bool sel = cbit && (bin < T);
    unsigned long long bb = __ballot(sel);
    int lane = t & 63;
    int wb = s - lane;
    if (lane == 0 && wb < 100032) {
        sbOut[(wb >> 5)]     = (uint32_t)bb;
        sbOut[(wb >> 5) + 1] = (uint32_t)(bb >> 32);
    }
    if (cbit && bin == T) {
        int idx = atomicAdd(&scal[iter], 1);
        if (idx < NLIST) glist[idx] = s;
    }
    // zero this block's own cand range (same range read above -> race-free)
    int d0 = b * 64;
    if (t < 64 && d0 + t < TWON / 4) cand32[d0 + t] = 0;
    if (t == 0) {
        __threadfence();
        int old = __hip_atomic_fetch_add(&scal[4 + iter], 1, __ATOMIC_ACQ_REL, __HIP_MEMORY_SCOPE_AGENT);
        lastFlag = (old == (int)gridDim.x - 1);
    }
    __syncthreads();
    if (!lastFlag) return;
    int n = aload(&scal[iter]); if (n > NLIST) n = NLIST;
    for (int j = t; j < n; j += 256) {
        int sj = aload(&glist[j]);
        llist[j] = sj;
        lscore[j] = uscore(ka, kb, (uint32_t)sj);
    }
    __syncthreads();
    for (int x = t; x < n; x += 256) {
        int st = llist[x];
        float ut = lscore[x];
        int rk = 0;
        for (int j = 0; j < n; ++j) {
            float uj = lscore[j];
            int sj = llist[j];
            rk += (uj < ut || (uj == ut && sj < st)) ? 1 : 0;
        }
        if (rk < R && st < NNODES) atomicOr(&sbOut[st >> 5], 1u << (st & 31));
    }
}

// final mark + LDS nibble-histogram degree -> NPLANE partial planes
__global__ __launch_bounds__(512) void k_markdeg(
        const int4* __restrict__ r4, const int4* __restrict__ c4, int E4,
        const uint32_t* __restrict__ sb, unsigned char* __restrict__ mk,
        uint32_t* __restrict__ planes) {
    __shared__ uint32_t h_[12500];
    for (int j = threadIdx.x; j < 12500; j += 512) h_[j] = 0;
    __syncthreads();
    for (int i = blockIdx.x * 512 + threadIdx.x; i < E4; i += NPLANE * 512) {
        ix4 r = ntload4(&r4[i]), c = ntload4(&c4[i]);
        uint32_t m = mk[i], nm = m;
        if (!(nm & 1u) && sbtest(sb, r.x, c.x)) nm |= 1u;
        if (!(nm & 2u) && sbtest(sb, r.y, c.y)) nm |= 2u;
        if (!(nm & 4u) && sbtest(sb, r.z, c.z)) nm |= 4u;
        if (!(nm & 8u) && sbtest(sb, r.w, c.w)) nm |= 8u;
        if (nm != m) mk[i] = (unsigned char)nm;
        if (!(nm & 1u)) atomicAdd(&h_[r.x >> 3], 1u << ((r.x & 7) * 4));
        if (!(nm & 2u)) atomicAdd(&h_[r.y >> 3], 1u << ((r.y & 7) * 4));
        if (!(nm & 4u)) atomicAdd(&h_[r.z >> 3], 1u << ((r.z & 7) * 4));
        if (!(nm & 8u)) atomicAdd(&h_[r.w >> 3], 1u << ((r.w & 7) * 4));
    }
    __syncthreads();
    uint32_t* mine = planes + blockIdx.x * 12500;
    for (int j = threadIdx.x; j < 12500; j += 512)
        __builtin_nontemporal_store(h_[j], &mine[j]);
}

// sum NPLANE nibble planes (packed-byte, per-node degree < 256 -> byte lanes
// never overflow), emit dinv
__global__ void k_reduce(const uint32_t* __restrict__ planes,
                         float* __restrict__ dinv) {
    int gid = blockIdx.x * blockDim.x + threadIdx.x;
    if (gid >= 25000) return;
    int col = gid >> 1;
    int half = gid & 1;
    uint32_t lo = 0, hi = 0;
    int p0 = half * (NPLANE / 2);
    #pragma unroll 8
    for (int p = p0; p < p0 + NPLANE / 2; ++p) {
        uint32_t v = __builtin_nontemporal_load(&planes[p * 12500 + col]);
        lo += v & 0x0F0F0F0Fu;
        hi += (v >> 4) & 0x0F0F0F0Fu;
    }
    lo += __shfl_xor(lo, 1);
    hi += __shfl_xor(hi, 1);
    if (half == 0) {
        int nbase = col * 8;
        #pragma unroll
        for (int q = 0; q < 4; ++q) {
            float d0 = (float)((lo >> (8 * q)) & 0xFFu);
            float d1 = (float)((hi >> (8 * q)) & 0xFFu);
            dinv[nbase + 2 * q]     = rsqrtf(d0 + 1e-12f);
            dinv[nbase + 2 * q + 1] = rsqrtf(d1 + 1e-12f);
        }
    }
}

__global__ __launch_bounds__(256) void k_out(
        const int4* __restrict__ r4, const int4* __restrict__ c4, int E4,
        const unsigned char* __restrict__ mk, const float* __restrict__ dinv,
        float4* __restrict__ enc4, float4* __restrict__ msk4) {
    int i = blockIdx.x * blockDim.x + threadIdx.x;
    if (i >= E4) return;
    ix4 r = ntload4(&r4[i]), c = ntload4(&c4[i]);
    uint32_t m = __builtin_nontemporal_load(&mk[i]);
    fx4 ev, mv;
    ev.x = (m & 1u) ? 0.0f : dinv[r.x] * dinv[c.x];  mv.x = (m & 1u) ? 1.0f : 0.0f;
    ev.y = (m & 2u) ? 0.0f : dinv[r.y] * dinv[c.y];  mv.y = (m & 2u) ? 1.0f : 0.0f;
    ev.z = (m & 4u) ? 0.0f : dinv[r.z] * dinv[c.z];  mv.z = (m & 4u) ? 1.0f : 0.0f;
    ev.w = (m & 8u) ? 0.0f : dinv[r.w] * dinv[c.w];  mv.w = (m & 8u) ? 1.0f : 0.0f;
    __builtin_nontemporal_store(ev, reinterpret_cast<fx4*>(&enc4[i]));
    __builtin_nontemporal_store(mv, reinterpret_cast<fx4*>(&msk4[i]));
}

extern "C" void kernel_launch(void* const* d_in, const int* in_sizes, int n_in,
                              void* d_out, int out_size, void* d_ws, size_t ws_size,
                              hipStream_t stream) {
    const int4* rows4 = (const int4*)d_in[0];
    const int4* cols4 = (const int4*)d_in[1];
    const int* seeds  = (const int*)d_in[3];
    int E      = in_sizes[0];    // 3,200,000
    int nSeeds = in_sizes[3];
    int E4     = E / 4;          // 800,000

    float* enc = (float*)d_out;
    float4* enc4p = (float4*)d_out;
    float4* msk4p = (float4*)(enc + E);
    uint32_t* planes = (uint32_t*)d_out;   // 256*12500*4 = 12.8 MB scratch in enc half

    // ws: [zeroed region: cand | hist0 | hist1 | scal] [sb0 sb1 sb2 dinv glist mk]
    char* p = (char*)d_ws;
    unsigned char* cand = (unsigned char*)p; p += TWON;   // 200,000 B
    int* hist0      = (int*)p;      p += NBINS * 4;
    int* hist1      = (int*)p;      p += NBINS * 4;
    int* scal       = (int*)p;      p += 16 * 4;
    size_t zlen = (size_t)(p - (char*)d_ws);              // 216,448 B
    uint32_t* sb0 = (uint32_t*)p;   p += SBW * 4;
    uint32_t* sb1 = (uint32_t*)p;   p += SBW * 4;
    uint32_t* sb2 = (uint32_t*)p;   p += SBW * 4;
    float* dinv   = (float*)p;      p += NNODES * 4;
    int* glist    = (int*)p;        p += NLIST * 4;
    unsigned char* mk = (unsigned char*)p; p += E4;       // 800 KB

    uint32_t ka0, kb0, ka1, kb1;
    tf2x32(0u, 42u, 0u, 0u, ka0, kb0);
    tf2x32(0u, 42u, 0u, 1u, ka1, kb1);

    int gE4 = (E4 + 255) / 256;              // 3125
    int gSR = (TWON + 255) / 256;            // 782
    int gHS = (TWON + 1023) / 1024;          // 196
    int nz  = (int)(zlen / 4);               // 54,112 dwords
    int gZ  = (nz + 255) / 256 + 1;          // 213 (block 0 = seed build)

    k_init<<<gZ, 256, 0, stream>>>(seeds, nSeeds, sb0, (uint32_t*)d_ws, nz);
    k_mark0<<<gE4, 256, 0, stream>>>(rows4, cols4, sb0, mk, cand, E4);
    k_histscan<<<gHS, 1024, 0, stream>>>(cand, hist0, scal, 0, ka0, kb0);
    k_selrank<<<gSR, 256, 0, stream>>>((uint32_t*)cand, cand, sb1, scal, glist,
                                       0, ka0, kb0);
    k_mark1<<<gE4, 256, 0, stream>>>(rows4, cols4, sb1, mk, cand, E4);
    k_histscan<<<gHS, 1024, 0, stream>>>(cand, hist1, scal, 1, ka1, kb1);
    k_selrank<<<gSR, 256, 0, stream>>>((uint32_t*)cand, cand, sb2, scal, glist,
                                       1, ka1, kb1);
    k_markdeg<<<NPLANE, 512, 0, stream>>>(rows4, cols4, E4, sb2, mk, planes);
    k_reduce<<<(25000 + 255) / 256, 256, 0, stream>>>(planes, dinv);
    k_out<<<gE4, 256, 0, stream>>>(rows4, cols4, E4, mk, dinv, enc4p, msk4p);
}

// Round 14
// 154.422 us; speedup vs baseline: 1.0652x; 1.0652x over previous
//
#include <hip/hip_runtime.h>
#include <cstdint>

// RandomMaskSubgraphs — R14: revert R13's nontemporal LOADS (regression:
// edge arrays [51MB] are Infinity-Cache-resident after the first pass;
// nt loads bypassed the LLC and cost +10us). This is R12 verbatim — the
// measured-best 154.6us configuration:
//  - init-once seed bitmask (k_init block 0) + zero region (blocks 1..212)
//  - plain cached loads for all streams; nt STORES only for write-once
//    outputs (k_out enc/msk) and the markdeg plane dump
//  - NPLANE 256 (all CUs), LDS nibble degree histogram, packed-byte reduce
//  - exact Threefry-2x32-20 partitionable PRNG + 2048-bin k-smallest
//    selection with (score,index) stable tie-break
// All numeric logic verbatim from absmax-0.0 rounds (R1/R4/R9/R12).

#define NNODES 100000
#define TWON   200000
#define NBINS  2048
#define SBW    3136     // node-bitmask dwords (3127 used)
#define NLIST  2048
#define NPLANE 256

typedef float fx4 __attribute__((ext_vector_type(4)));

__host__ __device__ inline uint32_t rotl32(uint32_t v, int d) {
    return (v << d) | (v >> (32 - d));
}

__host__ __device__ inline void tf2x32(uint32_t k0, uint32_t k1,
                                       uint32_t x0, uint32_t x1,
                                       uint32_t& y0, uint32_t& y1) {
    uint32_t k2 = k0 ^ k1 ^ 0x1BD11BDAu;
    x0 += k0; x1 += k1;
    #pragma unroll
    for (int g = 0; g < 5; ++g) {
        const int ra[4] = {13, 15, 26, 6};
        const int rb[4] = {17, 29, 16, 24};
        if ((g & 1) == 0) {
            #pragma unroll
            for (int j = 0; j < 4; ++j) { x0 += x1; x1 = rotl32(x1, ra[j]); x1 ^= x0; }
        } else {
            #pragma unroll
            for (int j = 0; j < 4; ++j) { x0 += x1; x1 = rotl32(x1, rb[j]); x1 ^= x0; }
        }
        uint32_t ks[3] = {k0, k1, k2};
        x0 += ks[(g + 1) % 3];
        x1 += ks[(g + 2) % 3] + (uint32_t)(g + 1);
    }
    y0 = x0; y1 = x1;
}

__device__ inline float uscore(uint32_t ka, uint32_t kb, uint32_t s) {
    uint32_t y0, y1;
    tf2x32(ka, kb, 0u, s, y0, y1);
    uint32_t fb = 0x3f800000u | ((y0 ^ y1) >> 9);
    return __uint_as_float(fb) - 1.0f;
}

__device__ inline uint32_t sbtest(const uint32_t* sb, int a, int b) {
    return ((sb[a >> 5] >> (a & 31)) | (sb[b >> 5] >> (b & 31))) & 1u;
}

__device__ inline int aload(const int* p) {
    return __hip_atomic_load(p, __ATOMIC_RELAXED, __HIP_MEMORY_SCOPE_AGENT);
}

__device__ inline int binof(float u) {
    int b = (int)(u * 2048.0f);
    return (b > NBINS - 1) ? NBINS - 1 : b;
}

// scal: [0]=cnt0 [1]=cnt1 [2]=tick_h0 [3]=tick_h1 [4]=tick_s0 [5]=tick_s1
//       [8]=T0 [9]=R0 [10]=T1 [11]=R1   (zeroed by k_init each launch)

// init: block 0 builds seed bitmask in LDS and dumps to global sb0;
// blocks 1..gZ zero the [cand | hist0 | hist1 | scal] region.
__global__ __launch_bounds__(256) void k_init(
        const int* __restrict__ seeds, int nSeeds,
        uint32_t* __restrict__ sb0, uint32_t* __restrict__ z, int nz) {
    __shared__ uint32_t seedb[SBW];
    const int t = threadIdx.x;
    if (blockIdx.x == 0) {
        for (int j = t; j < SBW; j += 256) seedb[j] = 0;
        __syncthreads();
        for (int j = t; j < nSeeds; j += 256) {
            int s = seeds[j];
            if (s < NNODES) atomicOr(&seedb[s >> 5], 1u << (s & 31));
        }
        __syncthreads();
        for (int j = t; j < SBW; j += 256) sb0[j] = seedb[j];
    } else {
        int i = (blockIdx.x - 1) * 256 + t;
        if (i < nz) z[i] = 0;
    }
}

// mark iteration 0: global seed bitmask (12.5KB, cache-resident), mk written
// unconditionally; cand byte stores (benign races, plain stores).
__global__ __launch_bounds__(256) void k_mark0(
        const int4* __restrict__ r4, const int4* __restrict__ c4,
        const uint32_t* __restrict__ sb,
        unsigned char* __restrict__ mk, unsigned char* __restrict__ cand,
        int E4) {
    const int i = blockIdx.x * 256 + threadIdx.x;
    if (i >= E4) return;
    int4 r = r4[i], c = c4[i];
    uint32_t m = 0;
    if (sbtest(sb, r.x, c.x)) { m |= 1u; cand[r.x + c.x] = 1; }
    if (sbtest(sb, r.y, c.y)) { m |= 2u; cand[r.y + c.y] = 1; }
    if (sbtest(sb, r.z, c.z)) { m |= 4u; cand[r.z + c.z] = 1; }
    if (sbtest(sb, r.w, c.w)) { m |= 8u; cand[r.w + c.w] = 1; }
    mk[i] = (unsigned char)m;
}

// mark iteration 1: mk RMW.
__global__ __launch_bounds__(256) void k_mark1(
        const int4* __restrict__ r4, const int4* __restrict__ c4,
        const uint32_t* __restrict__ sb,
        unsigned char* __restrict__ mk, unsigned char* __restrict__ cand,
        int E4) {
    const int i = blockIdx.x * 256 + threadIdx.x;
    if (i >= E4) return;
    int4 r = r4[i], c = c4[i];
    uint32_t m = mk[i], nm = m;
    if (!(nm & 1u) && sbtest(sb, r.x, c.x)) { nm |= 1u; cand[r.x + c.x] = 1; }
    if (!(nm & 2u) && sbtest(sb, r.y, c.y)) { nm |= 2u; cand[r.y + c.y] = 1; }
    if (!(nm & 4u) && sbtest(sb, r.z, c.z)) { nm |= 4u; cand[r.z + c.z] = 1; }
    if (!(nm & 8u) && sbtest(sb, r.w, c.w)) { nm |= 8u; cand[r.w + c.w] = 1; }
    if (nm != m) mk[i] = (unsigned char)nm;
}

// histogram of candidate score bins; last block scans -> T,R in scal.
__global__ __launch_bounds__(1024) void k_histscan(
        const unsigned char* __restrict__ cand,
        int* __restrict__ hist, int* __restrict__ scal, int iter,
        uint32_t ka, uint32_t kb) {
    __shared__ int lh[NBINS];
    __shared__ int part[1024];
    __shared__ int lastFlag;
    int t = threadIdx.x;
    int s = blockIdx.x * 1024 + t;
    lh[t] = 0; lh[t + 1024] = 0;
    __syncthreads();
    if (s < TWON && cand[s]) {
        atomicAdd(&lh[binof(uscore(ka, kb, (uint32_t)s))], 1);
    }
    __syncthreads();
    if (lh[t]) atomicAdd(&hist[t], lh[t]);
    if (lh[t + 1024]) atomicAdd(&hist[t + 1024], lh[t + 1024]);
    if (t == 0) {
        __threadfence();
        int old = __hip_atomic_fetch_add(&scal[2 + iter], 1, __ATOMIC_ACQ_REL, __HIP_MEMORY_SCOPE_AGENT);
        lastFlag = (old == (int)gridDim.x - 1);
    }
    __syncthreads();
    if (!lastFlag) return;
    // last-block tail: scan 2048 bins -> threshold bin T, in-bin rank R
    int h0 = aload(&hist[2 * t]);
    int h1 = aload(&hist[2 * t + 1]);
    part[t] = h0 + h1;
    __syncthreads();
    for (int d = 1; d < 1024; d <<= 1) {
        int w = (t >= d) ? part[t - d] : 0;
        __syncthreads();
        part[t] += w;
        __syncthreads();
    }
    int total = part[1023];
    int k = total >> (iter + 1);        // floor(count * 0.5^(i+1)), exact
    int base = (t > 0) ? part[t - 1] : 0;
    if (total > 0) {
        if (h0 > 0 && base <= k && k < base + h0) { scal[8 + 2 * iter] = 2 * t;     scal[9 + 2 * iter] = k - base; }
        int b2 = base + h0;
        if (h1 > 0 && b2 <= k && k < b2 + h1)     { scal[8 + 2 * iter] = 2 * t + 1; scal[9 + 2 * iter] = k - b2; }
    }
}

// select: bits (bin<T) via ballot; boundary bin -> glist; zero cand slice;
// last-block exact stable rank tail.
__global__ __launch_bounds__(256) void k_selrank(
        uint32_t* __restrict__ cand32, const unsigned char* __restrict__ cand,
        uint32_t* __restrict__ sbOut, int* __restrict__ scal,
        int* __restrict__ glist, int iter, uint32_t ka, uint32_t kb) {
    __shared__ int lastFlag;
    __shared__ int llist[NLIST];
    __shared__ float lscore[NLIST];
    const int t = threadIdx.x;
    const int b = blockIdx.x;
    const int s = b * 256 + t;
    const int T = scal[8 + 2 * iter];
    const int R = scal[9 + 2 * iter];
    bool cbit = (s < TWON) && cand[s];
    int bin = cbit ? binof(uscore(ka, kb, (uint32_t)s)) : -1;
    bool sel = cbit && (bin < T);
    unsigned long long bb = __ballot(sel);
    int lane = t & 63;
    int wb = s - lane;
    if (lane == 0 && wb < 100032) {
        sbOut[(wb >> 5)]     = (uint32_t)bb;
        sbOut[(wb >> 5) + 1] = (uint32_t)(bb >> 32);
    }
    if (cbit && bin == T) {
        int idx = atomicAdd(&scal[iter], 1);
        if (idx < NLIST) glist[idx] = s;
    }
    // zero this block's own cand range (same range read above -> race-free)
    int d0 = b * 64;
    if (t < 64 && d0 + t < TWON / 4) cand32[d0 + t] = 0;
    if (t == 0) {
        __threadfence();
        int old = __hip_atomic_fetch_add(&scal[4 + iter], 1, __ATOMIC_ACQ_REL, __HIP_MEMORY_SCOPE_AGENT);
        lastFlag = (old == (int)gridDim.x - 1);
    }
    __syncthreads();
    if (!lastFlag) return;
    int n = aload(&scal[iter]); if (n > NLIST) n = NLIST;
    for (int j = t; j < n; j += 256) {
        int sj = aload(&glist[j]);
        llist[j] = sj;
        lscore[j] = uscore(ka, kb, (uint32_t)sj);
    }
    __syncthreads();
    for (int x = t; x < n; x += 256) {
        int st = llist[x];
        float ut = lscore[x];
        int rk = 0;
        for (int j = 0; j < n; ++j) {
            float uj = lscore[j];
            int sj = llist[j];
            rk += (uj < ut || (uj == ut && sj < st)) ? 1 : 0;
        }
        if (rk < R && st < NNODES) atomicOr(&sbOut[st >> 5], 1u << (st & 31));
    }
}

// final mark + LDS nibble-histogram degree -> NPLANE partial planes
__global__ __launch_bounds__(512) void k_markdeg(
        const int4* __restrict__ r4, const int4* __restrict__ c4, int E4,
        const uint32_t* __restrict__ sb, unsigned char* __restrict__ mk,
        uint32_t* __restrict__ planes) {
    __shared__ uint32_t h_[12500];
    for (int j = threadIdx.x; j < 12500; j += 512) h_[j] = 0;
    __syncthreads();
    for (int i = blockIdx.x * 512 + threadIdx.x; i < E4; i += NPLANE * 512) {
        int4 r = r4[i], c = c4[i];
        uint32_t m = mk[i], nm = m;
        if (!(nm & 1u) && sbtest(sb, r.x, c.x)) nm |= 1u;
        if (!(nm & 2u) && sbtest(sb, r.y, c.y)) nm |= 2u;
        if (!(nm & 4u) && sbtest(sb, r.z, c.z)) nm |= 4u;
        if (!(nm & 8u) && sbtest(sb, r.w, c.w)) nm |= 8u;
        if (nm != m) mk[i] = (unsigned char)nm;
        if (!(nm & 1u)) atomicAdd(&h_[r.x >> 3], 1u << ((r.x & 7) * 4));
        if (!(nm & 2u)) atomicAdd(&h_[r.y >> 3], 1u << ((r.y & 7) * 4));
        if (!(nm & 4u)) atomicAdd(&h_[r.z >> 3], 1u << ((r.z & 7) * 4));
        if (!(nm & 8u)) atomicAdd(&h_[r.w >> 3], 1u << ((r.w & 7) * 4));
    }
    __syncthreads();
    uint32_t* mine = planes + blockIdx.x * 12500;
    for (int j = threadIdx.x; j < 12500; j += 512)
        __builtin_nontemporal_store(h_[j], &mine[j]);
}

// sum NPLANE nibble planes (packed-byte, per-node degree < 256 -> byte lanes
// never overflow), emit dinv
__global__ void k_reduce(const uint32_t* __restrict__ planes,
                         float* __restrict__ dinv) {
    int gid = blockIdx.x * blockDim.x + threadIdx.x;
    if (gid >= 25000) return;
    int col = gid >> 1;
    int half = gid & 1;
    uint32_t lo = 0, hi = 0;
    int p0 = half * (NPLANE / 2);
    #pragma unroll 8
    for (int p = p0; p < p0 + NPLANE / 2; ++p) {
        uint32_t v = planes[p * 12500 + col];
        lo += v & 0x0F0F0F0Fu;
        hi += (v >> 4) & 0x0F0F0F0Fu;
    }
    lo += __shfl_xor(lo, 1);
    hi += __shfl_xor(hi, 1);
    if (half == 0) {
        int nbase = col * 8;
        #pragma unroll
        for (int q = 0; q < 4; ++q) {
            float d0 = (float)((lo >> (8 * q)) & 0xFFu);
            float d1 = (float)((hi >> (8 * q)) & 0xFFu);
            dinv[nbase + 2 * q]     = rsqrtf(d0 + 1e-12f);
            dinv[nbase + 2 * q + 1] = rsqrtf(d1 + 1e-12f);
        }
    }
}

__global__ __launch_bounds__(256) void k_out(
        const int4* __restrict__ r4, const int4* __restrict__ c4, int E4,
        const unsigned char* __restrict__ mk, const float* __restrict__ dinv,
        float4* __restrict__ enc4, float4* __restrict__ msk4) {
    int i = blockIdx.x * blockDim.x + threadIdx.x;
    if (i >= E4) return;
    int4 r = r4[i], c = c4[i];
    uint32_t m = mk[i];
    fx4 ev, mv;
    ev.x = (m & 1u) ? 0.0f : dinv[r.x] * dinv[c.x];  mv.x = (m & 1u) ? 1.0f : 0.0f;
    ev.y = (m & 2u) ? 0.0f : dinv[r.y] * dinv[c.y];  mv.y = (m & 2u) ? 1.0f : 0.0f;
    ev.z = (m & 4u) ? 0.0f : dinv[r.z] * dinv[c.z];  mv.z = (m & 4u) ? 1.0f : 0.0f;
    ev.w = (m & 8u) ? 0.0f : dinv[r.w] * dinv[c.w];  mv.w = (m & 8u) ? 1.0f : 0.0f;
    __builtin_nontemporal_store(ev, reinterpret_cast<fx4*>(&enc4[i]));
    __builtin_nontemporal_store(mv, reinterpret_cast<fx4*>(&msk4[i]));
}

extern "C" void kernel_launch(void* const* d_in, const int* in_sizes, int n_in,
                              void* d_out, int out_size, void* d_ws, size_t ws_size,
                              hipStream_t stream) {
    const int4* rows4 = (const int4*)d_in[0];
    const int4* cols4 = (const int4*)d_in[1];
    const int* seeds  = (const int*)d_in[3];
    int E      = in_sizes[0];    // 3,200,000
    int nSeeds = in_sizes[3];
    int E4     = E / 4;          // 800,000

    float* enc = (float*)d_out;
    float4* enc4p = (float4*)d_out;
    float4* msk4p = (float4*)(enc + E);
    uint32_t* planes = (uint32_t*)d_out;   // 256*12500*4 = 12.8 MB scratch in enc half

    // ws: [zeroed region: cand | hist0 | hist1 | scal] [sb0 sb1 sb2 dinv glist mk]
    char* p = (char*)d_ws;
    unsigned char* cand = (unsigned char*)p; p += TWON;   // 200,000 B
    int* hist0      = (int*)p;      p += NBINS * 4;
    int* hist1      = (int*)p;      p += NBINS * 4;
    int* scal       = (int*)p;      p += 16 * 4;
    size_t zlen = (size_t)(p - (char*)d_ws);              // 216,448 B
    uint32_t* sb0 = (uint32_t*)p;   p += SBW * 4;
    uint32_t* sb1 = (uint32_t*)p;   p += SBW * 4;
    uint32_t* sb2 = (uint32_t*)p;   p += SBW * 4;
    float* dinv   = (float*)p;      p += NNODES * 4;
    int* glist    = (int*)p;        p += NLIST * 4;
    unsigned char* mk = (unsigned char*)p; p += E4;       // 800 KB

    uint32_t ka0, kb0, ka1, kb1;
    tf2x32(0u, 42u, 0u, 0u, ka0, kb0);
    tf2x32(0u, 42u, 0u, 1u, ka1, kb1);

    int gE4 = (E4 + 255) / 256;              // 3125
    int gSR = (TWON + 255) / 256;            // 782
    int gHS = (TWON + 1023) / 1024;          // 196
    int nz  = (int)(zlen / 4);               // 54,112 dwords
    int gZ  = (nz + 255) / 256 + 1;          // 213 (block 0 = seed build)

    k_init<<<gZ, 256, 0, stream>>>(seeds, nSeeds, sb0, (uint32_t*)d_ws, nz);
    k_mark0<<<gE4, 256, 0, stream>>>(rows4, cols4, sb0, mk, cand, E4);
    k_histscan<<<gHS, 1024, 0, stream>>>(cand, hist0, scal, 0, ka0, kb0);
    k_selrank<<<gSR, 256, 0, stream>>>((uint32_t*)cand, cand, sb1, scal, glist,
                                       0, ka0, kb0);
    k_mark1<<<gE4, 256, 0, stream>>>(rows4, cols4, sb1, mk, cand, E4);
    k_histscan<<<gHS, 1024, 0, stream>>>(cand, hist1, scal, 1, ka1, kb1);
    k_selrank<<<gSR, 256, 0, stream>>>((uint32_t*)cand, cand, sb2, scal, glist,
                                       1, ka1, kb1);
    k_markdeg<<<NPLANE, 512, 0, stream>>>(rows4, cols4, E4, sb2, mk, planes);
    k_reduce<<<(25000 + 255) / 256, 256, 0, stream>>>(planes, dinv);
    k_out<<<gE4, 256, 0, stream>>>(rows4, cols4, E4, mk, dinv, enc4p, msk4p);
}